// Round 1
// baseline (701.870 us; speedup 1.0000x reference)
//
#include <hip/hip_runtime.h>
#include <cstdint>
#include <cstddef>

#define HW    262144          // 512*512
#define BATCH 4
#define C     64
#define K     19
#define NPIX  (BATCH * HW)    // 1048576
#define NTILE (NPIX / 64)     // 16384
#define TILES_PER_B 4096      // HW/64
#define TAUINV (1.0f / 0.07f)

// ws layout:
//   +0     unsigned num_pos
//   +4     float    loss_sum
//   +16    float    k0[19*64]   (4864 B)
//   +8192  float    k0n[19*64]
//   +65536 unsigned pm[NPIX]    (4 MB, optional)

// ---------------- Kernel 1: prototypes k0[k][c] + num_pos + packed mask ----
__global__ __launch_bounds__(64) void k1_proto(
    const float* __restrict__ feat, const int* __restrict__ gt,
    float* __restrict__ k0, unsigned* __restrict__ num_pos,
    unsigned* __restrict__ pm)
{
    __shared__ float    sf[64][65];   // [channel][pixel], pad -> 2-way alias (free)
    __shared__ unsigned msk[64];
    const int lane = threadIdx.x;

    float acc[K];
#pragma unroll
    for (int k = 0; k < K; ++k) acc[k] = 0.0f;
    unsigned npos = 0;

    for (int tile = blockIdx.x; tile < NTILE; tile += gridDim.x) {
        const int b   = tile / TILES_PER_B;
        const int hw0 = (tile % TILES_PER_B) << 6;

        // ---- mask build: lane = pixel; coalesced per-k reads
        {
            const int* gp = gt + (size_t)b * K * HW + hw0 + lane;
            unsigned m = 0;
#pragma unroll
            for (int k = 0; k < K; ++k)
                m |= (gp[(size_t)k * HW] == 1) ? (1u << k) : 0u;
            npos += __popc(m);
            msk[lane] = m;
            if (pm) pm[(size_t)tile * 64 + lane] = m;
        }

        // ---- stage feat tile: 64ch x 64px, float4 coalesced
        {
            const float* fb = feat + (size_t)b * C * HW + hw0;
#pragma unroll
            for (int i = 0; i < 16; ++i) {
                int v  = lane + (i << 6);
                int c  = v >> 4;
                int p0 = (v & 15) << 2;
                const float4 val = *(const float4*)(fb + (size_t)c * HW + p0);
                sf[c][p0 + 0] = val.x; sf[c][p0 + 1] = val.y;
                sf[c][p0 + 2] = val.z; sf[c][p0 + 3] = val.w;
            }
        }
        __syncthreads();

        // ---- accumulate: lane = channel, loop pixels; mask is wave-uniform
        for (int p = 0; p < 64; ++p) {
            float f = sf[lane][p];
            unsigned ms = __builtin_amdgcn_readfirstlane(msk[p]);
#pragma unroll
            for (int k = 0; k < K; ++k)
                if (ms & (1u << k)) acc[k] += f;   // uniform scalar branch
        }
        __syncthreads();
    }

    // ---- global reduce: coalesced f32 atomics, 19 per lane
#pragma unroll
    for (int k = 0; k < K; ++k)
        atomicAdd(&k0[k * 64 + lane], acc[k]);

    for (int off = 32; off; off >>= 1) npos += __shfl_down(npos, off);
    if (lane == 0) atomicAdd(num_pos, npos);
}

// ---------------- Kernel 2: normalize prototypes --------------------------
__global__ __launch_bounds__(256) void k2_norm(
    const float* __restrict__ k0, float* __restrict__ k0n)
{
    __shared__ float rn[K];
    const int t = threadIdx.x;
    if (t < K) {
        float s = 0.0f;
        for (int c = 0; c < 64; ++c) { float v = k0[t * 64 + c]; s = fmaf(v, v, s); }
        rn[t] = 1.0f / fmaxf(sqrtf(s), 1e-12f);
    }
    __syncthreads();
    for (int i = t; i < K * 64; i += 256) k0n[i] = k0[i] * rn[i >> 6];
}

// ---------------- Kernel 3: logits + log-softmax + masked NLL sum ---------
__global__ __launch_bounds__(64) void k3_loss(
    const float* __restrict__ feat, const int* __restrict__ gt,
    const float* __restrict__ k0n, const unsigned* __restrict__ pm,
    float* __restrict__ loss_sum)
{
    __shared__ __align__(16) float sf[64][64];  // [channel][pixel], no pad needed
    __shared__ float w[K * 64];
    const int lane = threadIdx.x;

    for (int i = lane; i < K * 64; i += 64) w[i] = k0n[i];

    float lsum = 0.0f;

    for (int tile = blockIdx.x; tile < NTILE; tile += gridDim.x) {
        const int b   = tile / TILES_PER_B;
        const int hw0 = (tile % TILES_PER_B) << 6;

        // ---- per-pixel mask (lane = pixel)
        unsigned m;
        if (pm) {
            m = pm[(size_t)tile * 64 + lane];
        } else {
            const int* gp = gt + (size_t)b * K * HW + hw0 + lane;
            m = 0;
#pragma unroll
            for (int k = 0; k < K; ++k)
                m |= (gp[(size_t)k * HW] == 1) ? (1u << k) : 0u;
        }

        // ---- stage feat tile, float4 both sides
        {
            const float* fb = feat + (size_t)b * C * HW + hw0;
#pragma unroll
            for (int i = 0; i < 16; ++i) {
                int v  = lane + (i << 6);
                int c  = v >> 4;
                int p4 = (v & 15);
                float4 val = *(const float4*)(fb + (size_t)c * HW + (p4 << 2));
                ((float4*)&sf[c][0])[p4] = val;
            }
        }
        __syncthreads();

        // ---- dots: lane = pixel; k0n reads broadcast (conflict-free)
        float dot[K];
#pragma unroll
        for (int k = 0; k < K; ++k) dot[k] = 0.0f;
        float ss = 0.0f;
        for (int c = 0; c < 64; ++c) {
            float f = sf[c][lane];
            ss = fmaf(f, f, ss);
#pragma unroll
            for (int k = 0; k < K; ++k)
                dot[k] = fmaf(w[k * 64 + c], f, dot[k]);
        }

        const float sc = (1.0f / fmaxf(sqrtf(ss), 1e-12f)) * TAUINV;
        float mx = -1e30f;
#pragma unroll
        for (int k = 0; k < K; ++k) { dot[k] *= sc; mx = fmaxf(mx, dot[k]); }
        float se = 0.0f;
#pragma unroll
        for (int k = 0; k < K; ++k) se += expf(dot[k] - mx);
        const float logZ = mx + logf(se);
#pragma unroll
        for (int k = 0; k < K; ++k)
            lsum += (m & (1u << k)) ? (logZ - dot[k]) : 0.0f;

        __syncthreads();
    }

    for (int off = 32; off; off >>= 1) lsum += __shfl_down(lsum, off);
    if (lane == 0) atomicAdd(loss_sum, lsum);
}

// ---------------- Kernel 4: finalize --------------------------------------
__global__ void k4_final(const float* __restrict__ loss_sum,
                         const unsigned* __restrict__ num_pos,
                         float* __restrict__ out)
{
    out[0] = loss_sum[0] / (float)num_pos[0];
}

// ---------------- launch ---------------------------------------------------
extern "C" void kernel_launch(void* const* d_in, const int* in_sizes, int n_in,
                              void* d_out, int out_size, void* d_ws, size_t ws_size,
                              hipStream_t stream)
{
    const float* feat = (const float*)d_in[0];
    const int*   gt   = (const int*)d_in[1];
    float*       out  = (float*)d_out;

    char* ws = (char*)d_ws;
    unsigned* num_pos  = (unsigned*)(ws + 0);
    float*    loss_sum = (float*)(ws + 4);
    float*    k0       = (float*)(ws + 16);
    float*    k0n      = (float*)(ws + 8192);
    unsigned* pm       = nullptr;
    if (ws_size >= 65536 + sizeof(unsigned) * (size_t)NPIX)
        pm = (unsigned*)(ws + 65536);

    hipMemsetAsync(d_ws, 0, 16384, stream);  // zero num_pos/loss_sum/k0

    k1_proto<<<2048, 64, 0, stream>>>(feat, gt, k0, num_pos, pm);
    k2_norm <<<1,    256, 0, stream>>>(k0, k0n);
    k3_loss <<<2048, 64, 0, stream>>>(feat, gt, k0n, pm, loss_sum);
    k4_final<<<1,    1,   0, stream>>>(loss_sum, num_pos, out);
}